// Round 6
// baseline (428.079 us; speedup 1.0000x reference)
//
#include <hip/hip_runtime.h>
#include <hip/hip_cooperative_groups.h>
#include <stdint.h>

// Problem constants (fixed by the reference: B=2048, K=6144, MU=2,
// G0 = 1 + D^2 (feedback), G1 = 1 + D + D^2 (parity)).
#define KLEN  6144
#define BROWS 2048
#define NG    (BROWS / 32)      // 64 bit-groups of 32 rows
#define GK    (NG * KLEN)       // u32 words per packed plane = 393216
#define NT    256               // threads per block
#define CL    (KLEN / NT)       // 24 — EVEN, required so M^CL == I
#define QTOT  (BROWS * (3 * KLEN / 4))   // output float4 count = 9437184
#define COOP_MAX_BLK 1024
#define EMIT_BLK 2048

typedef float vfloat4 __attribute__((ext_vector_type(4)));  // native vec for nt-store

// RSC recursion (bitwise over 32 rows packed in a u32):
//   fb = u ^ s1;  par = u ^ s0;  (s0,s1) <- (fb, s0)
// State map's linear part M satisfies M^2 = I, so for even-length chunks the
// actual chunk init = XOR of preceding chunks' zero-init end states.

// ---------------------------------------------------------------------------
// Phase A body: pack 4 consecutive t's of group g. task in [0, GK/4).
__device__ __forceinline__ void pack_body(int task, const float* __restrict__ bits,
                                          uint32_t* __restrict__ packedS) {
    int g  = task / (KLEN / 4);
    int tq = task - g * (KLEN / 4);
    const float* rb = bits + (size_t)g * 32 * KLEN + 4 * tq;
    uint32_t w0 = 0, w1 = 0, w2 = 0, w3 = 0;
#pragma unroll 1
    for (int j0 = 0; j0 < 32; j0 += 8) {
#pragma unroll
        for (int j = 0; j < 8; ++j) {
            float4 f = *(const float4*)(rb + (size_t)(j0 + j) * KLEN);
            w0 |= (f.x > 0.5f ? 1u : 0u) << (j0 + j);
            w1 |= (f.y > 0.5f ? 1u : 0u) << (j0 + j);
            w2 |= (f.z > 0.5f ? 1u : 0u) << (j0 + j);
            w3 |= (f.w > 0.5f ? 1u : 0u) << (j0 + j);
        }
    }
    *(uint4*)(packedS + g * KLEN + 4 * tq) = make_uint4(w0, w1, w2, w3);
}

// ---------------------------------------------------------------------------
// Phase B body: one block-task blk = (enc, g); thread c owns chunk c (CL steps).
__device__ __forceinline__ void scan_body(int blk, int c,
                                          const uint32_t* __restrict__ packedS,
                                          const int* __restrict__ perm,
                                          uint32_t* __restrict__ p1,
                                          uint32_t* __restrict__ p2,
                                          uint32_t* a0, uint32_t* a1) {
    int enc = blk >> 6;
    int g   = blk & (NG - 1);
    const uint32_t* base = packedS + g * KLEN;
    int t0 = c * CL;

    uint32_t u[CL];
    if (enc) {
#pragma unroll
        for (int i = 0; i < CL; ++i) u[i] = base[perm[t0 + i]];
    } else {
#pragma unroll
        for (int i = 0; i < CL; ++i) u[i] = base[t0 + i];
    }

    // zero-init chunk scan -> end state
    uint32_t s0 = 0, s1 = 0;
#pragma unroll
    for (int i = 0; i < CL; ++i) { uint32_t n0 = u[i] ^ s1; s1 = s0; s0 = n0; }

    // block-wide XOR prefix (Hillis-Steele), then exclusive
    a0[c] = s0; a1[c] = s1;
    __syncthreads();
#pragma unroll
    for (int off = 1; off < NT; off <<= 1) {
        uint32_t x0 = 0, x1 = 0;
        if (c >= off) { x0 = a0[c - off]; x1 = a1[c - off]; }
        __syncthreads();
        a0[c] ^= x0; a1[c] ^= x1;
        __syncthreads();
    }
    s0 = c ? a0[c - 1] : 0u;
    s1 = c ? a1[c - 1] : 0u;

    // rescan with actual init, emit packed parities (uint4 every 4 steps)
    uint32_t* __restrict__ pout = enc ? p2 : p1;
    uint32_t pq0, pq1, pq2;
#pragma unroll
    for (int i = 0; i < CL; ++i) {
        uint32_t pv = u[i] ^ s0;
        uint32_t n0 = u[i] ^ s1; s1 = s0; s0 = n0;
        if ((i & 3) == 0) pq0 = pv;
        else if ((i & 3) == 1) pq1 = pv;
        else if ((i & 3) == 2) pq2 = pv;
        else *(uint4*)(pout + g * KLEN + t0 + i - 3) = make_uint4(pq0, pq1, pq2, pv);
    }
}

// ---------------------------------------------------------------------------
// Phase C body: one output float4 at quad index q (lane-contiguous stores).
__device__ __forceinline__ void emit_body(int q,
                                          const uint32_t* __restrict__ ps,
                                          const uint32_t* __restrict__ p1,
                                          const uint32_t* __restrict__ p2,
                                          float* __restrict__ out) {
    int b    = q / (3 * KLEN / 4);              // 4608 quads per row
    int qpos = q - b * (3 * KLEN / 4);
    int pos0 = 4 * qpos;
    uint32_t t0 = (uint32_t)(((uint64_t)(uint32_t)pos0 * 0xAAAAAAABULL) >> 33);
    int r0 = pos0 - 3 * (int)t0;                // pos0 % 3
    int g = b >> 5, bit = b & 31;

    const uint32_t* ps_ = ps + g * KLEN;
    const uint32_t* q1_ = p1 + g * KLEN;
    const uint32_t* q2_ = p2 + g * KLEN;
    uint32_t t1 = t0 + 1 < KLEN ? t0 + 1 : KLEN - 1;   // t0<=6142 in practice
    uint32_t w00 = ps_[t0], w01 = q1_[t0], w02 = q2_[t0];
    uint32_t w10 = ps_[t1], w11 = q1_[t1], w12 = q2_[t1];

    // element s: pos = pos0+s, comp = pos%3 (0=sys,1=p1,2=p2), time = t0+(r0+s>=3)
    uint32_t e0 = r0 == 0 ? w00 : (r0 == 1 ? w01 : w02);
    uint32_t e1 = r0 == 0 ? w01 : (r0 == 1 ? w02 : w10);
    uint32_t e2 = r0 == 0 ? w02 : (r0 == 1 ? w10 : w11);
    uint32_t e3 = r0 == 0 ? w10 : (r0 == 1 ? w11 : w12);

    vfloat4 f;
    f.x = (float)((e0 >> bit) & 1u);
    f.y = (float)((e1 >> bit) & 1u);
    f.z = (float)((e2 >> bit) & 1u);
    f.w = (float)((e3 >> bit) & 1u);
    __builtin_nontemporal_store(f, (vfloat4*)(out + (size_t)4 * q));
}

// ---------------------------------------------------------------------------
// Fused cooperative kernel: runtime grid, grid-stride in every phase.
__global__ __launch_bounds__(NT, 4) void turbo_fused_kernel(
        const float* __restrict__ bits, const int* __restrict__ perm,
        uint32_t* __restrict__ packedS, uint32_t* __restrict__ p1,
        uint32_t* __restrict__ p2, float* __restrict__ out) {
    cooperative_groups::grid_group grid = cooperative_groups::this_grid();
    const int nthr = gridDim.x * NT;
    const int tid = blockIdx.x * NT + threadIdx.x;

    for (int task = tid; task < GK / 4; task += nthr)
        pack_body(task, bits, packedS);
    __threadfence();
    grid.sync();

    __shared__ uint32_t a0[NT], a1[NT];
    for (int blk = blockIdx.x; blk < 2 * NG; blk += gridDim.x) {
        scan_body(blk, threadIdx.x, packedS, perm, p1, p2, a0, a1);
        __syncthreads();   // a0/a1 reused next iteration
    }
    __threadfence();
    grid.sync();

    for (int q = tid; q < QTOT; q += nthr)
        emit_body(q, packedS, p1, p2, out);
}

// ---------------------------------------------------------------------------
// Fallback kernels (plain launches, proven structure).
__global__ __launch_bounds__(NT) void pack_kernel(const float* __restrict__ bits,
                                                  uint32_t* __restrict__ packedS) {
    pack_body(blockIdx.x * NT + threadIdx.x, bits, packedS);
}

__global__ __launch_bounds__(NT) void scan_kernel(const uint32_t* __restrict__ packedS,
                                                  const int* __restrict__ perm,
                                                  uint32_t* __restrict__ p1,
                                                  uint32_t* __restrict__ p2) {
    __shared__ uint32_t a0[NT], a1[NT];
    scan_body(blockIdx.x, threadIdx.x, packedS, perm, p1, p2, a0, a1);
}

__global__ __launch_bounds__(NT) void emit_kernel(const uint32_t* __restrict__ ps,
                                                  const uint32_t* __restrict__ p1,
                                                  const uint32_t* __restrict__ p2,
                                                  float* __restrict__ out) {
    for (int q = blockIdx.x * NT + threadIdx.x; q < QTOT; q += EMIT_BLK * NT)
        emit_body(q, ps, p1, p2, out);
}

// ---------------------------------------------------------------------------
extern "C" void kernel_launch(void* const* d_in, const int* in_sizes, int n_in,
                              void* d_out, int out_size, void* d_ws, size_t ws_size,
                              hipStream_t stream) {
    const float* bits = (const float*)d_in[0];   // [B*K] float 0/1
    const int*   perm = (const int*)d_in[1];     // [K] int32
    float* out = (float*)d_out;                  // [B * 3K] float

    uint32_t* ws = (uint32_t*)d_ws;
    uint32_t* packedS = ws;                      // [GK]
    uint32_t* p1      = ws + (size_t)GK;         // [GK]
    uint32_t* p2      = ws + (size_t)2 * GK;     // [GK]

    // Host-side, stream-free, deterministic queries (legal under graph capture).
    int dev = 0;
    (void)hipGetDevice(&dev);
    int coop = 0, nCU = 0, maxBlk = 0;
    (void)hipDeviceGetAttribute(&coop, hipDeviceAttributeCooperativeLaunch, dev);
    (void)hipDeviceGetAttribute(&nCU, hipDeviceAttributeMultiprocessorCount, dev);
    (void)hipOccupancyMaxActiveBlocksPerMultiprocessor(&maxBlk, turbo_fused_kernel, NT, 0);

    bool launched = false;
    if (coop && nCU > 0 && maxBlk > 0) {
        int grid = maxBlk * nCU;
        if (grid > COOP_MAX_BLK) grid = COOP_MAX_BLK;
        void* args[] = { (void*)&bits, (void*)&perm, (void*)&packedS,
                         (void*)&p1, (void*)&p2, (void*)&out };
        hipError_t e = hipLaunchCooperativeKernel((const void*)turbo_fused_kernel,
                                                  dim3(grid), dim3(NT), args, 0, stream);
        launched = (e == hipSuccess);
    }
    if (!launched) {
        hipLaunchKernelGGL(pack_kernel, dim3(GK / 4 / NT), dim3(NT), 0, stream,
                           bits, packedS);
        hipLaunchKernelGGL(scan_kernel, dim3(2 * NG), dim3(NT), 0, stream,
                           packedS, perm, p1, p2);
        hipLaunchKernelGGL(emit_kernel, dim3(EMIT_BLK), dim3(NT), 0, stream,
                           packedS, p1, p2, out);
    }
}

// Round 7
// 52.244 us; speedup vs baseline: 8.1938x; 8.1938x over previous
//
#include <hip/hip_runtime.h>
#include <stdint.h>

// Problem constants (fixed by the reference: B=2048, K=6144, MU=2,
// G0 = 1 + D^2 (feedback), G1 = 1 + D + D^2 (parity)).
#define KLEN  6144
#define BROWS 2048
#define NG    (BROWS / 32)      // 64 bit-groups of 32 rows
#define GK    (NG * KLEN)       // u32 words per packed plane = 393216
#define NT    256               // threads per block
#define CL    (KLEN / NT)       // 24 — EVEN, required so M^CL == I
#define QTOT  (BROWS * (3 * KLEN / 4))   // output float4 count = 9437184
#define EMIT_BLK 2048

typedef float vfloat4 __attribute__((ext_vector_type(4)));  // native vec for nt-store

// RSC recursion (bitwise over 32 rows packed in a u32):
//   fb = u ^ s1;  par = u ^ s0;  (s0,s1) <- (fb, s0)
// State map's linear part M satisfies M^2 = I, so for even-length chunks the
// actual chunk init = XOR of preceding chunks' zero-init end states.
//
// NOTE (round 6 post-mortem): the single cooperative kernel version spent
// ~380 of 428 us in grid.sync() spin barriers (VALUBusy 3.3%, HBM 5.5%).
// Kernel-boundary barriers inside the captured graph are ~2 us each — use
// three plain dispatches.

// ---------------------------------------------------------------------------
// Kernel A: bit-pack bits[B][K] -> packedS[g*K + t] (bit j = row g*32+j).
// Thread = (g, quad-of-t): 32 float4 loads (16 B/lane, 1 KB/wave/row-iter),
// one uint4 store. Exactly GK/4 = 98304 threads.
__global__ __launch_bounds__(NT) void pack_kernel(const float* __restrict__ bits,
                                                  uint32_t* __restrict__ packedS) {
    int task = blockIdx.x * NT + threadIdx.x;    // [0, GK/4)
    int g  = task / (KLEN / 4);
    int tq = task - g * (KLEN / 4);
    const float* rb = bits + (size_t)g * 32 * KLEN + 4 * tq;
    uint32_t w0 = 0, w1 = 0, w2 = 0, w3 = 0;
#pragma unroll 1
    for (int j0 = 0; j0 < 32; j0 += 8) {
#pragma unroll
        for (int j = 0; j < 8; ++j) {
            float4 f = *(const float4*)(rb + (size_t)(j0 + j) * KLEN);
            w0 |= (f.x > 0.5f ? 1u : 0u) << (j0 + j);
            w1 |= (f.y > 0.5f ? 1u : 0u) << (j0 + j);
            w2 |= (f.z > 0.5f ? 1u : 0u) << (j0 + j);
            w3 |= (f.w > 0.5f ? 1u : 0u) << (j0 + j);
        }
    }
    *(uint4*)(packedS + g * KLEN + 4 * tq) = make_uint4(w0, w1, w2, w3);
}

// ---------------------------------------------------------------------------
// Kernel B: fused parallel scan. Block = (enc, g); thread c owns chunk c
// (CL=24 steps). Zero-init scan -> end states; block-wide XOR prefix
// (Hillis-Steele in LDS); rescan from corrected init using register-cached
// u[], emit packed parities as aligned uint4 stores.
__global__ __launch_bounds__(NT) void scan_kernel(const uint32_t* __restrict__ packedS,
                                                  const int* __restrict__ perm,
                                                  uint32_t* __restrict__ p1,
                                                  uint32_t* __restrict__ p2) {
    __shared__ uint32_t a0[NT], a1[NT];
    int c   = threadIdx.x;
    int enc = blockIdx.x >> 6;        // 0 or 1
    int g   = blockIdx.x & (NG - 1);
    const uint32_t* base = packedS + g * KLEN;
    int t0 = c * CL;

    uint32_t u[CL];
    if (enc) {
#pragma unroll
        for (int i = 0; i < CL; ++i) u[i] = base[perm[t0 + i]];
    } else {
#pragma unroll
        for (int i = 0; i < CL; ++i) u[i] = base[t0 + i];
    }

    // zero-init chunk scan -> end state
    uint32_t s0 = 0, s1 = 0;
#pragma unroll
    for (int i = 0; i < CL; ++i) { uint32_t n0 = u[i] ^ s1; s1 = s0; s0 = n0; }

    // block-wide XOR prefix (Hillis-Steele), then exclusive
    a0[c] = s0; a1[c] = s1;
    __syncthreads();
#pragma unroll
    for (int off = 1; off < NT; off <<= 1) {
        uint32_t x0 = 0, x1 = 0;
        if (c >= off) { x0 = a0[c - off]; x1 = a1[c - off]; }
        __syncthreads();
        a0[c] ^= x0; a1[c] ^= x1;
        __syncthreads();
    }
    s0 = c ? a0[c - 1] : 0u;
    s1 = c ? a1[c - 1] : 0u;

    // rescan with actual init, emit packed parities (uint4 every 4 steps)
    uint32_t* __restrict__ pout = enc ? p2 : p1;
    uint32_t pq0, pq1, pq2;
#pragma unroll
    for (int i = 0; i < CL; ++i) {
        uint32_t pv = u[i] ^ s0;
        uint32_t n0 = u[i] ^ s1; s1 = s0; s0 = n0;
        if ((i & 3) == 0) pq0 = pv;
        else if ((i & 3) == 1) pq1 = pv;
        else if ((i & 3) == 2) pq2 = pv;
        else *(uint4*)(pout + g * KLEN + t0 + i - 3) = make_uint4(pq0, pq1, pq2, pv);
    }
}

// ---------------------------------------------------------------------------
// Kernel C: emit codeword [sys, p1, p2] interleaved. One float4 per iter per
// thread, lane-contiguous (wave writes 1 KB contiguous per store instr).
// Plane reads are L2-resident dword loads; nontemporal stores keep the
// 151 MB output stream from evicting the planes.
__global__ __launch_bounds__(NT) void emit_kernel(const uint32_t* __restrict__ ps,
                                                  const uint32_t* __restrict__ p1,
                                                  const uint32_t* __restrict__ p2,
                                                  float* __restrict__ out) {
    for (int q = blockIdx.x * NT + threadIdx.x; q < QTOT; q += EMIT_BLK * NT) {
        int b    = q / (3 * KLEN / 4);              // 4608 quads per row
        int qpos = q - b * (3 * KLEN / 4);
        int pos0 = 4 * qpos;
        uint32_t t0 = (uint32_t)(((uint64_t)(uint32_t)pos0 * 0xAAAAAAABULL) >> 33);
        int r0 = pos0 - 3 * (int)t0;                // pos0 % 3
        int g = b >> 5, bit = b & 31;

        const uint32_t* ps_ = ps + g * KLEN;
        const uint32_t* q1_ = p1 + g * KLEN;
        const uint32_t* q2_ = p2 + g * KLEN;
        uint32_t t1 = t0 + 1 < KLEN ? t0 + 1 : KLEN - 1;   // t0 <= 6142 in practice
        uint32_t w00 = ps_[t0], w01 = q1_[t0], w02 = q2_[t0];
        uint32_t w10 = ps_[t1], w11 = q1_[t1], w12 = q2_[t1];

        // element s: pos = pos0+s, comp = pos%3 (0=sys,1=p1,2=p2), time = t0+(r0+s>=3)
        uint32_t e0 = r0 == 0 ? w00 : (r0 == 1 ? w01 : w02);
        uint32_t e1 = r0 == 0 ? w01 : (r0 == 1 ? w02 : w10);
        uint32_t e2 = r0 == 0 ? w02 : (r0 == 1 ? w10 : w11);
        uint32_t e3 = r0 == 0 ? w10 : (r0 == 1 ? w11 : w12);

        vfloat4 f;
        f.x = (float)((e0 >> bit) & 1u);
        f.y = (float)((e1 >> bit) & 1u);
        f.z = (float)((e2 >> bit) & 1u);
        f.w = (float)((e3 >> bit) & 1u);
        __builtin_nontemporal_store(f, (vfloat4*)(out + (size_t)4 * q));
    }
}

// ---------------------------------------------------------------------------
extern "C" void kernel_launch(void* const* d_in, const int* in_sizes, int n_in,
                              void* d_out, int out_size, void* d_ws, size_t ws_size,
                              hipStream_t stream) {
    const float* bits = (const float*)d_in[0];   // [B*K] float 0/1
    const int*   perm = (const int*)d_in[1];     // [K] int32
    float* out = (float*)d_out;                  // [B * 3K] float

    uint32_t* ws = (uint32_t*)d_ws;
    uint32_t* packedS = ws;                      // [GK]
    uint32_t* p1      = ws + (size_t)GK;         // [GK]
    uint32_t* p2      = ws + (size_t)2 * GK;     // [GK]

    hipLaunchKernelGGL(pack_kernel, dim3(GK / 4 / NT), dim3(NT), 0, stream,
                       bits, packedS);
    hipLaunchKernelGGL(scan_kernel, dim3(2 * NG), dim3(NT), 0, stream,
                       packedS, perm, p1, p2);
    hipLaunchKernelGGL(emit_kernel, dim3(EMIT_BLK), dim3(NT), 0, stream,
                       packedS, p1, p2, out);
}

// Round 8
// 50.845 us; speedup vs baseline: 8.4192x; 1.0275x over previous
//
#include <hip/hip_runtime.h>
#include <stdint.h>

// Problem constants (fixed by the reference: B=2048, K=6144, MU=2,
// G0 = 1 + D^2 (feedback), G1 = 1 + D + D^2 (parity)).
#define KLEN  6144
#define BROWS 2048
#define NG    (BROWS / 32)      // 64 bit-groups of 32 rows
#define GK    (NG * KLEN)       // u32 words per packed plane = 393216
#define NT    256               // threads per block
#define CL    (KLEN / NT)       // 24 — EVEN, required so M^CL == I

// emit tiling: block = (g, tile of ET t's, octet of 8 rows)
#define ET    1024
#define NTILE (KLEN / ET)       // 6
#define RPB   8                 // rows per block
#define NRS   (32 / RPB)        // 4
#define EMIT_GRID (NG * NTILE * NRS)   // 1536

typedef float vfloat4 __attribute__((ext_vector_type(4)));  // native vec for nt ops

// RSC recursion (bitwise over 32 rows packed in a u32):
//   fb = u ^ s1;  par = u ^ s0;  (s0,s1) <- (fb, s0)
// State map's linear part M satisfies M^2 = I, so for even-length chunks the
// actual chunk init = XOR of preceding chunks' zero-init end states.
//
// Round-6 post-mortem: cooperative grid.sync() cost ~190 us/barrier on this
// chip (8 non-coherent XCD L2s). Kernel boundaries in the captured graph are
// ~2 us — keep three plain dispatches.

// ---------------------------------------------------------------------------
// Kernel A: bit-pack bits[B][K] -> packedS[g*K + t] (bit j = row g*32+j).
// Thread = (g, quad-of-t): 32 nontemporal float4 loads (read-once data —
// don't pollute L2), one uint4 store (cached: scan+emit re-read it).
__global__ __launch_bounds__(NT) void pack_kernel(const float* __restrict__ bits,
                                                  uint32_t* __restrict__ packedS) {
    int task = blockIdx.x * NT + threadIdx.x;    // [0, GK/4)
    int g  = task / (KLEN / 4);
    int tq = task - g * (KLEN / 4);
    const float* rb = bits + (size_t)g * 32 * KLEN + 4 * tq;
    uint32_t w0 = 0, w1 = 0, w2 = 0, w3 = 0;
#pragma unroll 1
    for (int j0 = 0; j0 < 32; j0 += 8) {
#pragma unroll
        for (int j = 0; j < 8; ++j) {
            vfloat4 f = __builtin_nontemporal_load(
                (const vfloat4*)(rb + (size_t)(j0 + j) * KLEN));
            w0 |= (f.x > 0.5f ? 1u : 0u) << (j0 + j);
            w1 |= (f.y > 0.5f ? 1u : 0u) << (j0 + j);
            w2 |= (f.z > 0.5f ? 1u : 0u) << (j0 + j);
            w3 |= (f.w > 0.5f ? 1u : 0u) << (j0 + j);
        }
    }
    *(uint4*)(packedS + g * KLEN + 4 * tq) = make_uint4(w0, w1, w2, w3);
}

// ---------------------------------------------------------------------------
// Kernel B: fused parallel scan. Block = (enc, g); thread c owns chunk c
// (CL=24 steps). Zero-init scan -> end states; block-wide XOR prefix
// (Hillis-Steele in LDS); rescan from corrected init using register-cached
// u[], emit packed parities as aligned uint4 stores.
__global__ __launch_bounds__(NT) void scan_kernel(const uint32_t* __restrict__ packedS,
                                                  const int* __restrict__ perm,
                                                  uint32_t* __restrict__ p1,
                                                  uint32_t* __restrict__ p2) {
    __shared__ uint32_t a0[NT], a1[NT];
    int c   = threadIdx.x;
    int enc = blockIdx.x >> 6;        // 0 or 1
    int g   = blockIdx.x & (NG - 1);
    const uint32_t* base = packedS + g * KLEN;
    int t0 = c * CL;

    uint32_t u[CL];
    if (enc) {
#pragma unroll
        for (int i = 0; i < CL; ++i) u[i] = base[perm[t0 + i]];
    } else {
#pragma unroll
        for (int i = 0; i < CL; ++i) u[i] = base[t0 + i];
    }

    // zero-init chunk scan -> end state
    uint32_t s0 = 0, s1 = 0;
#pragma unroll
    for (int i = 0; i < CL; ++i) { uint32_t n0 = u[i] ^ s1; s1 = s0; s0 = n0; }

    // block-wide XOR prefix (Hillis-Steele), then exclusive
    a0[c] = s0; a1[c] = s1;
    __syncthreads();
#pragma unroll
    for (int off = 1; off < NT; off <<= 1) {
        uint32_t x0 = 0, x1 = 0;
        if (c >= off) { x0 = a0[c - off]; x1 = a1[c - off]; }
        __syncthreads();
        a0[c] ^= x0; a1[c] ^= x1;
        __syncthreads();
    }
    s0 = c ? a0[c - 1] : 0u;
    s1 = c ? a1[c - 1] : 0u;

    // rescan with actual init, emit packed parities (uint4 every 4 steps)
    uint32_t* __restrict__ pout = enc ? p2 : p1;
    uint32_t pq0, pq1, pq2;
#pragma unroll
    for (int i = 0; i < CL; ++i) {
        uint32_t pv = u[i] ^ s0;
        uint32_t n0 = u[i] ^ s1; s1 = s0; s0 = n0;
        if ((i & 3) == 0) pq0 = pv;
        else if ((i & 3) == 1) pq1 = pv;
        else if ((i & 3) == 2) pq2 = pv;
        else *(uint4*)(pout + g * KLEN + t0 + i - 3) = make_uint4(pq0, pq1, pq2, pv);
    }
}

// ---------------------------------------------------------------------------
// Kernel C: emit codeword [sys, p1, p2] interleaved. Block = (g, tile, octet):
// stage 3x ET plane words in LDS (one uint4-coalesced pass), then emit 8 rows
// x 768 quads from LDS. Stores: wave-contiguous 1 KB nontemporal float4.
__global__ __launch_bounds__(NT) void emit_kernel(const uint32_t* __restrict__ ps,
                                                  const uint32_t* __restrict__ p1,
                                                  const uint32_t* __restrict__ p2,
                                                  float* __restrict__ out) {
    __shared__ uint32_t l0[ET], l1[ET], l2[ET];
    int blk  = blockIdx.x;
    int g    = blk / (NTILE * NRS);
    int rem  = blk - g * (NTILE * NRS);
    int tile = rem / NRS;
    int rs   = rem - tile * NRS;          // row-octet index
    int i    = threadIdx.x;

    size_t pbase = (size_t)g * KLEN + (size_t)tile * ET;
    *(uint4*)(l0 + 4 * i) = *(const uint4*)(ps + pbase + 4 * i);
    *(uint4*)(l1 + 4 * i) = *(const uint4*)(p1 + pbase + 4 * i);
    *(uint4*)(l2 + 4 * i) = *(const uint4*)(p2 + pbase + 4 * i);
    __syncthreads();

#pragma unroll 1
    for (int rr = 0; rr < RPB; ++rr) {
        int bit = rs * RPB + rr;                    // row within group = shift
        int b   = g * 32 + bit;
        float* rowout = out + (size_t)b * (3 * KLEN) + (size_t)tile * (3 * ET);
#pragma unroll
        for (int k = 0; k < 3; ++k) {
            int qq   = i + NT * k;                  // quad in [0, 768)
            int pos0 = 4 * qq;                      // position in [0, 3072)
            int t0   = pos0 / 3;                    // compiler magic-mul
            int r0   = pos0 - 3 * t0;
            uint32_t w00 = l0[t0],     w01 = l1[t0],     w02 = l2[t0];
            uint32_t w10 = l0[t0 + 1], w11 = l1[t0 + 1], w12 = l2[t0 + 1];
            // element s: pos=pos0+s, comp=(pos0+s)%3 (0=sys,1=p1,2=p2)
            uint32_t e0 = r0 == 0 ? w00 : (r0 == 1 ? w01 : w02);
            uint32_t e1 = r0 == 0 ? w01 : (r0 == 1 ? w02 : w10);
            uint32_t e2 = r0 == 0 ? w02 : (r0 == 1 ? w10 : w11);
            uint32_t e3 = r0 == 0 ? w10 : (r0 == 1 ? w11 : w12);
            vfloat4 f;
            f.x = (float)((e0 >> bit) & 1u);
            f.y = (float)((e1 >> bit) & 1u);
            f.z = (float)((e2 >> bit) & 1u);
            f.w = (float)((e3 >> bit) & 1u);
            __builtin_nontemporal_store(f, (vfloat4*)(rowout + (size_t)pos0));
        }
    }
}

// ---------------------------------------------------------------------------
extern "C" void kernel_launch(void* const* d_in, const int* in_sizes, int n_in,
                              void* d_out, int out_size, void* d_ws, size_t ws_size,
                              hipStream_t stream) {
    const float* bits = (const float*)d_in[0];   // [B*K] float 0/1
    const int*   perm = (const int*)d_in[1];     // [K] int32
    float* out = (float*)d_out;                  // [B * 3K] float

    uint32_t* ws = (uint32_t*)d_ws;
    uint32_t* packedS = ws;                      // [GK]
    uint32_t* p1      = ws + (size_t)GK;         // [GK]
    uint32_t* p2      = ws + (size_t)2 * GK;     // [GK]

    hipLaunchKernelGGL(pack_kernel, dim3(GK / 4 / NT), dim3(NT), 0, stream,
                       bits, packedS);
    hipLaunchKernelGGL(scan_kernel, dim3(2 * NG), dim3(NT), 0, stream,
                       packedS, perm, p1, p2);
    hipLaunchKernelGGL(emit_kernel, dim3(EMIT_GRID), dim3(NT), 0, stream,
                       packedS, p1, p2, out);
}

// Round 9
// 49.807 us; speedup vs baseline: 8.5947x; 1.0208x over previous
//
#include <hip/hip_runtime.h>
#include <stdint.h>

// Problem constants (fixed by the reference: B=2048, K=6144, MU=2,
// G0 = 1 + D^2 (feedback), G1 = 1 + D + D^2 (parity)).
#define KLEN  6144
#define BROWS 2048
#define NG    (BROWS / 32)      // 64 bit-groups of 32 rows
#define GK    (NG * KLEN)       // u32 words per packed plane = 393216
#define NT    256               // threads per block (pack/emit)

// scan: 512-thread blocks, thread-chunk CL2=12 (EVEN — required so M^CL == I)
#define NT2   512
#define CL2   (KLEN / NT2)      // 12

// emit tiling: block = (g, tile of ET t's, octet of 8 rows)
#define ET    1024
#define NTILE (KLEN / ET)       // 6
#define RPB   8                 // rows per block
#define NRS   (32 / RPB)        // 4
#define EMIT_GRID (NG * NTILE * NRS)   // 1536

typedef float vfloat4 __attribute__((ext_vector_type(4)));  // native vec for nt ops

// RSC recursion (bitwise over 32 rows packed in a u32):
//   fb = u ^ s1;  par = u ^ s0;  (s0,s1) <- (fb, s0)
// State map's linear part M satisfies M^2 = I, so for even-length chunks the
// actual chunk init = XOR of preceding chunks' zero-init end states.
//
// Round-6 post-mortem: cooperative grid.sync() cost ~190 us/barrier on this
// chip (8 non-coherent XCD L2s). Kernel boundaries in the captured graph are
// ~2 us — keep three plain dispatches.
// Round-8 post-mortem: emit issue-rate has ~5x headroom over the store-BW
// requirement — emit is near the write floor; remaining fat is pack's nt
// loads (unproven path) and scan's 24-deep serial chain.

// ---------------------------------------------------------------------------
// Kernel A: bit-pack bits[B][K] -> packedS[g*K + t] (bit j = row g*32+j).
// Thread = (g, quad-of-t): 32 plain float4 loads (the measured-ceiling path),
// one uint4 store.
__global__ __launch_bounds__(NT) void pack_kernel(const float* __restrict__ bits,
                                                  uint32_t* __restrict__ packedS) {
    int task = blockIdx.x * NT + threadIdx.x;    // [0, GK/4)
    int g  = task / (KLEN / 4);
    int tq = task - g * (KLEN / 4);
    const float* rb = bits + (size_t)g * 32 * KLEN + 4 * tq;
    uint32_t w0 = 0, w1 = 0, w2 = 0, w3 = 0;
#pragma unroll 1
    for (int j0 = 0; j0 < 32; j0 += 8) {
#pragma unroll
        for (int j = 0; j < 8; ++j) {
            float4 f = *(const float4*)(rb + (size_t)(j0 + j) * KLEN);
            w0 |= (f.x > 0.5f ? 1u : 0u) << (j0 + j);
            w1 |= (f.y > 0.5f ? 1u : 0u) << (j0 + j);
            w2 |= (f.z > 0.5f ? 1u : 0u) << (j0 + j);
            w3 |= (f.w > 0.5f ? 1u : 0u) << (j0 + j);
        }
    }
    *(uint4*)(packedS + g * KLEN + 4 * tq) = make_uint4(w0, w1, w2, w3);
}

// ---------------------------------------------------------------------------
// Kernel B: fused parallel scan. Block = (enc, g), 512 threads; thread c owns
// chunk c (CL2=12 steps). Zero-init scan -> end states; block-wide XOR prefix
// (Hillis-Steele in LDS, 9 rounds); rescan from corrected init using
// register-cached u[], emit packed parities as aligned uint4 stores.
__global__ __launch_bounds__(NT2) void scan_kernel(const uint32_t* __restrict__ packedS,
                                                   const int* __restrict__ perm,
                                                   uint32_t* __restrict__ p1,
                                                   uint32_t* __restrict__ p2) {
    __shared__ uint32_t a0[NT2], a1[NT2];
    int c   = threadIdx.x;
    int enc = blockIdx.x >> 6;        // 0 or 1
    int g   = blockIdx.x & (NG - 1);
    const uint32_t* base = packedS + g * KLEN;
    int t0 = c * CL2;

    uint32_t u[CL2];
    if (enc) {
#pragma unroll
        for (int i = 0; i < CL2; ++i) u[i] = base[perm[t0 + i]];
    } else {
#pragma unroll
        for (int i = 0; i < CL2; ++i) u[i] = base[t0 + i];
    }

    // zero-init chunk scan -> end state
    uint32_t s0 = 0, s1 = 0;
#pragma unroll
    for (int i = 0; i < CL2; ++i) { uint32_t n0 = u[i] ^ s1; s1 = s0; s0 = n0; }

    // block-wide XOR prefix (Hillis-Steele), then exclusive
    a0[c] = s0; a1[c] = s1;
    __syncthreads();
#pragma unroll
    for (int off = 1; off < NT2; off <<= 1) {
        uint32_t x0 = 0, x1 = 0;
        if (c >= off) { x0 = a0[c - off]; x1 = a1[c - off]; }
        __syncthreads();
        a0[c] ^= x0; a1[c] ^= x1;
        __syncthreads();
    }
    s0 = c ? a0[c - 1] : 0u;
    s1 = c ? a1[c - 1] : 0u;

    // rescan with actual init, emit packed parities (uint4 every 4 steps)
    uint32_t* __restrict__ pout = enc ? p2 : p1;
    uint32_t pq0, pq1, pq2;
#pragma unroll
    for (int i = 0; i < CL2; ++i) {
        uint32_t pv = u[i] ^ s0;
        uint32_t n0 = u[i] ^ s1; s1 = s0; s0 = n0;
        if ((i & 3) == 0) pq0 = pv;
        else if ((i & 3) == 1) pq1 = pv;
        else if ((i & 3) == 2) pq2 = pv;
        else *(uint4*)(pout + g * KLEN + t0 + i - 3) = make_uint4(pq0, pq1, pq2, pv);
    }
}

// ---------------------------------------------------------------------------
// Kernel C: emit codeword [sys, p1, p2] interleaved. Block = (g, tile, octet):
// stage 3x ET plane words in LDS (one uint4-coalesced pass), then emit 8 rows
// x 768 quads from LDS. Stores: wave-contiguous 1 KB nontemporal float4.
__global__ __launch_bounds__(NT) void emit_kernel(const uint32_t* __restrict__ ps,
                                                  const uint32_t* __restrict__ p1,
                                                  const uint32_t* __restrict__ p2,
                                                  float* __restrict__ out) {
    __shared__ uint32_t l0[ET], l1[ET], l2[ET];
    int blk  = blockIdx.x;
    int g    = blk / (NTILE * NRS);
    int rem  = blk - g * (NTILE * NRS);
    int tile = rem / NRS;
    int rs   = rem - tile * NRS;          // row-octet index
    int i    = threadIdx.x;

    size_t pbase = (size_t)g * KLEN + (size_t)tile * ET;
    *(uint4*)(l0 + 4 * i) = *(const uint4*)(ps + pbase + 4 * i);
    *(uint4*)(l1 + 4 * i) = *(const uint4*)(p1 + pbase + 4 * i);
    *(uint4*)(l2 + 4 * i) = *(const uint4*)(p2 + pbase + 4 * i);
    __syncthreads();

#pragma unroll 1
    for (int rr = 0; rr < RPB; ++rr) {
        int bit = rs * RPB + rr;                    // row within group = shift
        int b   = g * 32 + bit;
        float* rowout = out + (size_t)b * (3 * KLEN) + (size_t)tile * (3 * ET);
#pragma unroll
        for (int k = 0; k < 3; ++k) {
            int qq   = i + NT * k;                  // quad in [0, 768)
            int pos0 = 4 * qq;                      // position in [0, 3072)
            int t0   = pos0 / 3;                    // compiler magic-mul
            int r0   = pos0 - 3 * t0;
            uint32_t w00 = l0[t0],     w01 = l1[t0],     w02 = l2[t0];
            uint32_t w10 = l0[t0 + 1], w11 = l1[t0 + 1], w12 = l2[t0 + 1];
            // element s: pos=pos0+s, comp=(pos0+s)%3 (0=sys,1=p1,2=p2)
            uint32_t e0 = r0 == 0 ? w00 : (r0 == 1 ? w01 : w02);
            uint32_t e1 = r0 == 0 ? w01 : (r0 == 1 ? w02 : w10);
            uint32_t e2 = r0 == 0 ? w02 : (r0 == 1 ? w10 : w11);
            uint32_t e3 = r0 == 0 ? w10 : (r0 == 1 ? w11 : w12);
            vfloat4 f;
            f.x = (float)((e0 >> bit) & 1u);
            f.y = (float)((e1 >> bit) & 1u);
            f.z = (float)((e2 >> bit) & 1u);
            f.w = (float)((e3 >> bit) & 1u);
            __builtin_nontemporal_store(f, (vfloat4*)(rowout + (size_t)pos0));
        }
    }
}

// ---------------------------------------------------------------------------
extern "C" void kernel_launch(void* const* d_in, const int* in_sizes, int n_in,
                              void* d_out, int out_size, void* d_ws, size_t ws_size,
                              hipStream_t stream) {
    const float* bits = (const float*)d_in[0];   // [B*K] float 0/1
    const int*   perm = (const int*)d_in[1];     // [K] int32
    float* out = (float*)d_out;                  // [B * 3K] float

    uint32_t* ws = (uint32_t*)d_ws;
    uint32_t* packedS = ws;                      // [GK]
    uint32_t* p1      = ws + (size_t)GK;         // [GK]
    uint32_t* p2      = ws + (size_t)2 * GK;     // [GK]

    hipLaunchKernelGGL(pack_kernel, dim3(GK / 4 / NT), dim3(NT), 0, stream,
                       bits, packedS);
    hipLaunchKernelGGL(scan_kernel, dim3(2 * NG), dim3(NT2), 0, stream,
                       packedS, perm, p1, p2);
    hipLaunchKernelGGL(emit_kernel, dim3(EMIT_GRID), dim3(NT), 0, stream,
                       packedS, p1, p2, out);
}